// Round 7
// baseline (114.434 us; speedup 1.0000x reference)
//
#include <hip/hip_runtime.h>

#define NN 8192
#define DIN 128
#define DOUT 64

typedef __attribute__((ext_vector_type(8))) short short8;
typedef __attribute__((ext_vector_type(4))) float f32x4;

static __device__ __forceinline__ unsigned short f2bf(float x) {
  unsigned u = __builtin_bit_cast(unsigned, x);
  u = (u + 0x7FFFu + ((u >> 16) & 1u)) >> 16;
  return (unsigned short)u;
}

// nontemporal 16B load (NT cache bit: no-allocate/evict-first).
// NOTE: __builtin_nontemporal_load requires a clang ext_vector type,
// not HIP's float4 class.
static __device__ __forceinline__ f32x4 ldnt4(const float* p) {
  return __builtin_nontemporal_load(reinterpret_cast<const f32x4*>(p));
}

// Prologue: h = X@W (row per wave), f = h@a1, g = h@a2, and pack h into bf16
// MFMA B-fragment order: hbf[((jt*4+ns)*64 + lane)*8 + e] =
// bf16(h[jt*32 + (lane>>4)*8 + e][ns*16 + (lane&15)])
__global__ __launch_bounds__(256) void k_h(
    const float* __restrict__ x, const float* __restrict__ wmat,
    const float* __restrict__ avec, float* __restrict__ f,
    float* __restrict__ g, unsigned short* __restrict__ hbf) {
  const int t = threadIdx.x;
  const int lane = t & 63;                 // = output column
  const int row = blockIdx.x * 4 + (t >> 6);
  const float* xr = x + (size_t)row * DIN;
  float acc = 0.f;
#pragma unroll 8
  for (int k = 0; k < DIN; ++k) acc = fmaf(xr[k], wmat[k * DOUT + lane], acc);

  // f, g via full-wave butterfly reduce (lanes == columns)
  float fa = acc * avec[lane];
  float ga = acc * avec[DOUT + lane];
#pragma unroll
  for (int off = 32; off; off >>= 1) {
    fa += __shfl_xor(fa, off);
    ga += __shfl_xor(ga, off);
  }
  if (lane == 0) { f[row] = fa; g[row] = ga; }

  // scatter bf16(h) into fragment layout
  const int jt  = row >> 5;
  const int grp = (row >> 3) & 3;
  const int e   = row & 7;
  const int ns  = lane >> 4;
  const int l15 = lane & 15;
  hbf[((size_t)(jt * 4 + ns) * 64 + grp * 16 + l15) * 8 + e] = f2bf(acc);
}

// Main: fused masked-softmax(adj-modulated scores) @ h, flash style.
// 16-row stripe per block PAIR (blockIdx&1 = j-half). 4 waves split the
// half's j-range. Register pipeline; adj loads are NONTEMPORAL (the one-use
// 268MB stream should not allocate in L2 -- tests the L2-fill-path ceiling).
__global__ __launch_bounds__(256, 4) void k_main(
    const float* __restrict__ adj, const float* __restrict__ f,
    const float* __restrict__ g, const unsigned short* __restrict__ hbf,
    const float* __restrict__ acp, const float* __restrict__ bcp,
    float* __restrict__ pacc, float* __restrict__ pms) {
  const int t = threadIdx.x;
  const int wv = t >> 6, lane = t & 63;
  const int r = lane & 15, grp = lane >> 4;
  const int stripe = blockIdx.x >> 1;
  const int half = blockIdx.x & 1;
  const int i0 = stripe * 16;
  const float ac = acp[0], bc = bcp[0];
  const float fr = f[i0 + r];
  const float L2E = 1.4426950408889634f;
  const float MASKV = -9.0e15f;

  float m = MASKV, s = 0.f;
  f32x4 acc0 = {0.f, 0.f, 0.f, 0.f};
  f32x4 acc1 = acc0, acc2 = acc0, acc3 = acc0;

  const float* arow = adj + (size_t)(i0 + r) * NN;
  const int jt0 = half * 128 + wv;
  const int jtEnd = half * 128 + 128;

  // ---- pipeline prologue (issue order: A0, G0, A1) ----
  const int jb0 = jt0 * 32 + grp * 8;
  f32x4 Aa = ldnt4(arow + jb0);
  f32x4 Ab = ldnt4(arow + jb0 + 4);
  f32x4 Ga = *reinterpret_cast<const f32x4*>(g + jb0);
  f32x4 Gb = *reinterpret_cast<const f32x4*>(g + jb0 + 4);
  const int j1 = (jt0 + 4 < jtEnd ? jt0 + 4 : jt0) * 32 + grp * 8;
  f32x4 Ana = ldnt4(arow + j1);
  f32x4 Anb = ldnt4(arow + j1 + 4);

  for (int jt = jt0; jt < jtEnd; jt += 4) {
    // 1) issue B_k first (L2-resident fragments)
    const short8* bp = reinterpret_cast<const short8*>(hbf) + (size_t)jt * 256 + lane;
    const short8 B0 = bp[0], B1 = bp[64], B2 = bp[128], B3 = bp[192];

    // 2) scores from already-resident A_k, G_k
    const float av[8] = {Aa[0], Aa[1], Aa[2], Aa[3], Ab[0], Ab[1], Ab[2], Ab[3]};
    const float gv[8] = {Ga[0], Ga[1], Ga[2], Ga[3], Gb[0], Gb[1], Gb[2], Gb[3]};
    float sc[8];
    float tmax = MASKV;
#pragma unroll
    for (int e = 0; e < 8; ++e) {
      const float adjv = av[e];
      const float tl = fmaf(ac, adjv, bc);
      const float lr = fmaxf(tl, 0.2f * tl);   // leaky-relu slope 0.2
      float sv = lr * (fr + gv[e]);
      sv = adjv > 0.f ? sv : MASKV;            // mask
      sc[e] = sv;
      tmax = fmaxf(tmax, sv);
    }
    tmax = fmaxf(tmax, __shfl_xor(tmax, 16));
    tmax = fmaxf(tmax, __shfl_xor(tmax, 32));

    if (__any(tmax > m + 8.f)) {               // deferred rescale (T13, THR=8)
      const float mn = fmaxf(m, tmax);
      const float scale = exp2f((m - mn) * L2E);
      s *= scale;
      const float s0 = __shfl(scale, grp * 4 + 0);
      const float s1 = __shfl(scale, grp * 4 + 1);
      const float s2 = __shfl(scale, grp * 4 + 2);
      const float s3 = __shfl(scale, grp * 4 + 3);
      const f32x4 sv4 = {s0, s1, s2, s3};
      acc0 *= sv4; acc1 *= sv4; acc2 *= sv4; acc3 *= sv4;
      m = mn;
    }

    // 3) issue next-iter G, then next-next-iter A (A strictly last)
    const int jg = (jt + 4 < jtEnd ? jt + 4 : jt) * 32 + grp * 8;
    const f32x4 Gna = *reinterpret_cast<const f32x4*>(g + jg);
    const f32x4 Gnb = *reinterpret_cast<const f32x4*>(g + jg + 4);
    const int ja = (jt + 8 < jtEnd ? jt + 8 : jt) * 32 + grp * 8;
    const f32x4 A2a = ldnt4(arow + ja);
    const f32x4 A2b = ldnt4(arow + ja + 4);

    // 4) pack P to bf16
    const float mL = m * L2E;
    short8 afrag;
    float ps = 0.f;
#pragma unroll
    for (int e = 0; e < 8; ++e) {
      const float p = exp2f(fmaf(sc[e], L2E, -mL));
      ps += p;
      afrag[e] = (short)f2bf(p);
    }
    s += ps;

    // 5) MFMA (waits on B_k; leaves fresh G/A prefetches in flight)
    acc0 = __builtin_amdgcn_mfma_f32_16x16x32_bf16(afrag, B0, acc0, 0, 0, 0);
    acc1 = __builtin_amdgcn_mfma_f32_16x16x32_bf16(afrag, B1, acc1, 0, 0, 0);
    acc2 = __builtin_amdgcn_mfma_f32_16x16x32_bf16(afrag, B2, acc2, 0, 0, 0);
    acc3 = __builtin_amdgcn_mfma_f32_16x16x32_bf16(afrag, B3, acc3, 0, 0, 0);

    // rotate pipeline registers
    Aa = Ana; Ab = Anb; Ana = A2a; Anb = A2b; Ga = Gna; Gb = Gnb;
  }

  // full row-sum of s across the 4 lane-groups
  s += __shfl_xor(s, 16);
  s += __shfl_xor(s, 32);

  __shared__ float sm[4][16];
  __shared__ float ssum[4][16];
  __shared__ float sacc[4][16][65];  // +1 pad breaks bank conflicts
  if (grp == 0) { sm[wv][r] = m; ssum[wv][r] = s; }
#pragma unroll
  for (int reg = 0; reg < 4; ++reg) {
    sacc[wv][grp * 4 + reg][ 0 + r] = acc0[reg];
    sacc[wv][grp * 4 + reg][16 + r] = acc1[reg];
    sacc[wv][grp * 4 + reg][32 + r] = acc2[reg];
    sacc[wv][grp * 4 + reg][48 + r] = acc3[reg];
  }
  __syncthreads();

  // merge the block's 4 wave-partials, write block partial (M, S, acc)
  const int c = t & 63;
  float* paccB = pacc + (size_t)blockIdx.x * 16 * 64;
  float* pmsB  = pms  + (size_t)blockIdx.x * 32;
#pragma unroll
  for (int rr = 0; rr < 4; ++rr) {
    const int row = (t >> 6) * 4 + rr;  // 0..15
    const float M = fmaxf(fmaxf(sm[0][row], sm[1][row]),
                          fmaxf(sm[2][row], sm[3][row]));
    float S = 0.f, A = 0.f;
#pragma unroll
    for (int k = 0; k < 4; ++k) {
      const float e = exp2f((sm[k][row] - M) * L2E);
      S += ssum[k][row] * e;
      A += sacc[k][row][c] * e;
    }
    paccB[row * 64 + c] = A;
    if (c == 0) { pmsB[row * 2] = M; pmsB[row * 2 + 1] = S; }
  }
}

// Combine the two j-half partials per row, finish with ELU.
__global__ __launch_bounds__(256) void k_comb(
    const float* __restrict__ pacc, const float* __restrict__ pms,
    float* __restrict__ out) {
  const int idx = blockIdx.x * 256 + threadIdx.x;  // 0 .. 8192*64-1
  const int row = idx >> 6, c = idx & 63;
  const int stripe = row >> 4, rin = row & 15;
  const float L2E = 1.4426950408889634f;
  const size_t b0 = (size_t)stripe * 2, b1 = b0 + 1;
  const float m0 = pms[b0 * 32 + rin * 2], s0 = pms[b0 * 32 + rin * 2 + 1];
  const float m1 = pms[b1 * 32 + rin * 2], s1 = pms[b1 * 32 + rin * 2 + 1];
  const float M = fmaxf(m0, m1);
  const float e0 = exp2f((m0 - M) * L2E);
  const float e1 = exp2f((m1 - M) * L2E);
  const float A = pacc[b0 * 1024 + rin * 64 + c] * e0 +
                  pacc[b1 * 1024 + rin * 64 + c] * e1;
  const float S = s0 * e0 + s1 * e1;
  const float v = A / S;
  out[idx] = v > 0.f ? v : expm1f(v);
}

extern "C" void kernel_launch(void* const* d_in, const int* in_sizes, int n_in,
                              void* d_out, int out_size, void* d_ws, size_t ws_size,
                              hipStream_t stream) {
  const float* x    = (const float*)d_in[0];   // (1, 8192, 128)
  const float* adj  = (const float*)d_in[1];   // (8192, 8192)
  const float* wmat = (const float*)d_in[2];   // (128, 64)
  const float* avec = (const float*)d_in[3];   // (128, 1)
  const float* acp  = (const float*)d_in[4];   // scalar
  const float* bcp  = (const float*)d_in[5];   // scalar
  float* out = (float*)d_out;                  // (8192, 64) fp32

  // ws: f 32KB | g 32KB | hbf 1MB | pacc 4MB | pms 128KB
  float* f = (float*)d_ws;
  float* g = f + NN;
  unsigned short* hbf = (unsigned short*)(g + NN);
  float* pacc = (float*)(hbf + (size_t)NN * DOUT);
  float* pms  = pacc + (size_t)1024 * 16 * 64;

  k_h<<<NN / 4, 256, 0, stream>>>(x, wmat, avec, f, g, hbf);
  k_main<<<NN / 8, 256, 0, stream>>>(adj, f, g, hbf, acp, bcp, pacc, pms);
  k_comb<<<NN * DOUT / 256, 256, 0, stream>>>(pacc, pms, out);
}

// Round 8
// 92.139 us; speedup vs baseline: 1.2420x; 1.2420x over previous
//
#include <hip/hip_runtime.h>

#define NN 8192
#define DIN 128
#define DOUT 64
#define NT_STRIPES 80   // first 80*16 rows (~42MB) read nontemporal (evict-first)
                        // so the remaining ~226MB of adj stays L3-resident
                        // across graph replays (L3=256MB; thrash-defeat carve-out)

typedef __attribute__((ext_vector_type(8))) short short8;
typedef __attribute__((ext_vector_type(4))) float f32x4;

static __device__ __forceinline__ unsigned short f2bf(float x) {
  unsigned u = __builtin_bit_cast(unsigned, x);
  u = (u + 0x7FFFu + ((u >> 16) & 1u)) >> 16;
  return (unsigned short)u;
}

template <bool NT>
static __device__ __forceinline__ f32x4 ld4(const float* p) {
  if constexpr (NT)
    return __builtin_nontemporal_load(reinterpret_cast<const f32x4*>(p));
  else
    return *reinterpret_cast<const f32x4*>(p);
}

// Prologue: h = X@W (row per wave), f = h@a1, g = h@a2, and pack h into bf16
// MFMA B-fragment order: hbf[((jt*4+ns)*64 + lane)*8 + e] =
// bf16(h[jt*32 + (lane>>4)*8 + e][ns*16 + (lane&15)])
__global__ __launch_bounds__(256) void k_h(
    const float* __restrict__ x, const float* __restrict__ wmat,
    const float* __restrict__ avec, float* __restrict__ f,
    float* __restrict__ g, unsigned short* __restrict__ hbf) {
  const int t = threadIdx.x;
  const int lane = t & 63;                 // = output column
  const int row = blockIdx.x * 4 + (t >> 6);
  const float* xr = x + (size_t)row * DIN;
  float acc = 0.f;
#pragma unroll 8
  for (int k = 0; k < DIN; ++k) acc = fmaf(xr[k], wmat[k * DOUT + lane], acc);

  // f, g via full-wave butterfly reduce (lanes == columns)
  float fa = acc * avec[lane];
  float ga = acc * avec[DOUT + lane];
#pragma unroll
  for (int off = 32; off; off >>= 1) {
    fa += __shfl_xor(fa, off);
    ga += __shfl_xor(ga, off);
  }
  if (lane == 0) { f[row] = fa; g[row] = ga; }

  // scatter bf16(h) into fragment layout
  const int jt  = row >> 5;
  const int grp = (row >> 3) & 3;
  const int e   = row & 7;
  const int ns  = lane >> 4;
  const int l15 = lane & 15;
  hbf[((size_t)(jt * 4 + ns) * 64 + grp * 16 + l15) * 8 + e] = f2bf(acc);
}

// Main body: fused masked-softmax(adj-modulated scores) @ h, flash style.
// 16-row stripe per block PAIR (blockIdx&1 = j-half). 4 waves split the
// half's j-range; register software pipeline (A 2-deep, G 1-deep, B first).
template <bool NT>
static __device__ __forceinline__ void main_body(
    const float* __restrict__ adj, const float* __restrict__ f,
    const float* __restrict__ g, const unsigned short* __restrict__ hbf,
    const float* __restrict__ acp, const float* __restrict__ bcp,
    float* __restrict__ pacc, float* __restrict__ pms,
    int stripe, int half) {
  const int t = threadIdx.x;
  const int wv = t >> 6, lane = t & 63;
  const int r = lane & 15, grp = lane >> 4;
  const int i0 = stripe * 16;
  const float ac = acp[0], bc = bcp[0];
  const float fr = f[i0 + r];
  const float L2E = 1.4426950408889634f;
  const float MASKV = -9.0e15f;

  float m = MASKV, s = 0.f;
  f32x4 acc0 = {0.f, 0.f, 0.f, 0.f};
  f32x4 acc1 = acc0, acc2 = acc0, acc3 = acc0;

  const float* arow = adj + (size_t)(i0 + r) * NN;
  const int jt0 = half * 128 + wv;
  const int jtEnd = half * 128 + 128;

  // ---- pipeline prologue (issue order: A0, G0, A1) ----
  const int jb0 = jt0 * 32 + grp * 8;
  f32x4 Aa = ld4<NT>(arow + jb0);
  f32x4 Ab = ld4<NT>(arow + jb0 + 4);
  f32x4 Ga = *reinterpret_cast<const f32x4*>(g + jb0);
  f32x4 Gb = *reinterpret_cast<const f32x4*>(g + jb0 + 4);
  const int j1 = (jt0 + 4 < jtEnd ? jt0 + 4 : jt0) * 32 + grp * 8;
  f32x4 Ana = ld4<NT>(arow + j1);
  f32x4 Anb = ld4<NT>(arow + j1 + 4);

  for (int jt = jt0; jt < jtEnd; jt += 4) {
    // 1) issue B_k first (L2-resident fragments)
    const short8* bp = reinterpret_cast<const short8*>(hbf) + (size_t)jt * 256 + lane;
    const short8 B0 = bp[0], B1 = bp[64], B2 = bp[128], B3 = bp[192];

    // 2) scores from already-resident A_k, G_k
    const float av[8] = {Aa[0], Aa[1], Aa[2], Aa[3], Ab[0], Ab[1], Ab[2], Ab[3]};
    const float gv[8] = {Ga[0], Ga[1], Ga[2], Ga[3], Gb[0], Gb[1], Gb[2], Gb[3]};
    float sc[8];
    float tmax = MASKV;
#pragma unroll
    for (int e = 0; e < 8; ++e) {
      const float adjv = av[e];
      const float tl = fmaf(ac, adjv, bc);
      const float lr = fmaxf(tl, 0.2f * tl);   // leaky-relu slope 0.2
      float sv = lr * (fr + gv[e]);
      sv = adjv > 0.f ? sv : MASKV;            // mask
      sc[e] = sv;
      tmax = fmaxf(tmax, sv);
    }
    tmax = fmaxf(tmax, __shfl_xor(tmax, 16));
    tmax = fmaxf(tmax, __shfl_xor(tmax, 32));

    if (__any(tmax > m + 8.f)) {               // deferred rescale (T13, THR=8)
      const float mn = fmaxf(m, tmax);
      const float scale = exp2f((m - mn) * L2E);
      s *= scale;
      const float s0 = __shfl(scale, grp * 4 + 0);
      const float s1 = __shfl(scale, grp * 4 + 1);
      const float s2 = __shfl(scale, grp * 4 + 2);
      const float s3 = __shfl(scale, grp * 4 + 3);
      const f32x4 sv4 = {s0, s1, s2, s3};
      acc0 *= sv4; acc1 *= sv4; acc2 *= sv4; acc3 *= sv4;
      m = mn;
    }

    // 3) issue next-iter G, then next-next-iter A (A strictly last)
    const int jg = (jt + 4 < jtEnd ? jt + 4 : jt) * 32 + grp * 8;
    const f32x4 Gna = *reinterpret_cast<const f32x4*>(g + jg);
    const f32x4 Gnb = *reinterpret_cast<const f32x4*>(g + jg + 4);
    const int ja = (jt + 8 < jtEnd ? jt + 8 : jt) * 32 + grp * 8;
    const f32x4 A2a = ld4<NT>(arow + ja);
    const f32x4 A2b = ld4<NT>(arow + ja + 4);

    // 4) pack P to bf16
    const float mL = m * L2E;
    short8 afrag;
    float ps = 0.f;
#pragma unroll
    for (int e = 0; e < 8; ++e) {
      const float p = exp2f(fmaf(sc[e], L2E, -mL));
      ps += p;
      afrag[e] = (short)f2bf(p);
    }
    s += ps;

    // 5) MFMA (waits on B_k; leaves fresh G/A prefetches in flight)
    acc0 = __builtin_amdgcn_mfma_f32_16x16x32_bf16(afrag, B0, acc0, 0, 0, 0);
    acc1 = __builtin_amdgcn_mfma_f32_16x16x32_bf16(afrag, B1, acc1, 0, 0, 0);
    acc2 = __builtin_amdgcn_mfma_f32_16x16x32_bf16(afrag, B2, acc2, 0, 0, 0);
    acc3 = __builtin_amdgcn_mfma_f32_16x16x32_bf16(afrag, B3, acc3, 0, 0, 0);

    // rotate pipeline registers
    Aa = Ana; Ab = Anb; Ana = A2a; Anb = A2b; Ga = Gna; Gb = Gnb;
  }

  // full row-sum of s across the 4 lane-groups
  s += __shfl_xor(s, 16);
  s += __shfl_xor(s, 32);

  __shared__ float sm[4][16];
  __shared__ float ssum[4][16];
  __shared__ float sacc[4][16][65];  // +1 pad breaks bank conflicts
  if (grp == 0) { sm[wv][r] = m; ssum[wv][r] = s; }
#pragma unroll
  for (int reg = 0; reg < 4; ++reg) {
    sacc[wv][grp * 4 + reg][ 0 + r] = acc0[reg];
    sacc[wv][grp * 4 + reg][16 + r] = acc1[reg];
    sacc[wv][grp * 4 + reg][32 + r] = acc2[reg];
    sacc[wv][grp * 4 + reg][48 + r] = acc3[reg];
  }
  __syncthreads();

  // merge the block's 4 wave-partials, write block partial (M, S, acc)
  const int c = t & 63;
  const int bid = stripe * 2 + half;
  float* paccB = pacc + (size_t)bid * 16 * 64;
  float* pmsB  = pms  + (size_t)bid * 32;
#pragma unroll
  for (int rr = 0; rr < 4; ++rr) {
    const int row = (t >> 6) * 4 + rr;  // 0..15
    const float M = fmaxf(fmaxf(sm[0][row], sm[1][row]),
                          fmaxf(sm[2][row], sm[3][row]));
    float S = 0.f, A = 0.f;
#pragma unroll
    for (int k = 0; k < 4; ++k) {
      const float e = exp2f((sm[k][row] - M) * L2E);
      S += ssum[k][row] * e;
      A += sacc[k][row][c] * e;
    }
    paccB[row * 64 + c] = A;
    if (c == 0) { pmsB[row * 2] = M; pmsB[row * 2 + 1] = S; }
  }
}

__global__ __launch_bounds__(256, 4) void k_main(
    const float* __restrict__ adj, const float* __restrict__ f,
    const float* __restrict__ g, const unsigned short* __restrict__ hbf,
    const float* __restrict__ acp, const float* __restrict__ bcp,
    float* __restrict__ pacc, float* __restrict__ pms) {
  const int stripe = blockIdx.x >> 1;
  const int half = blockIdx.x & 1;
  if (stripe < NT_STRIPES)
    main_body<true>(adj, f, g, hbf, acp, bcp, pacc, pms, stripe, half);
  else
    main_body<false>(adj, f, g, hbf, acp, bcp, pacc, pms, stripe, half);
}

// Combine the two j-half partials per row, finish with ELU.
__global__ __launch_bounds__(256) void k_comb(
    const float* __restrict__ pacc, const float* __restrict__ pms,
    float* __restrict__ out) {
  const int idx = blockIdx.x * 256 + threadIdx.x;  // 0 .. 8192*64-1
  const int row = idx >> 6, c = idx & 63;
  const int stripe = row >> 4, rin = row & 15;
  const float L2E = 1.4426950408889634f;
  const size_t b0 = (size_t)stripe * 2, b1 = b0 + 1;
  const float m0 = pms[b0 * 32 + rin * 2], s0 = pms[b0 * 32 + rin * 2 + 1];
  const float m1 = pms[b1 * 32 + rin * 2], s1 = pms[b1 * 32 + rin * 2 + 1];
  const float M = fmaxf(m0, m1);
  const float e0 = exp2f((m0 - M) * L2E);
  const float e1 = exp2f((m1 - M) * L2E);
  const float A = pacc[b0 * 1024 + rin * 64 + c] * e0 +
                  pacc[b1 * 1024 + rin * 64 + c] * e1;
  const float S = s0 * e0 + s1 * e1;
  const float v = A / S;
  out[idx] = v > 0.f ? v : expm1f(v);
}

extern "C" void kernel_launch(void* const* d_in, const int* in_sizes, int n_in,
                              void* d_out, int out_size, void* d_ws, size_t ws_size,
                              hipStream_t stream) {
  const float* x    = (const float*)d_in[0];   // (1, 8192, 128)
  const float* adj  = (const float*)d_in[1];   // (8192, 8192)
  const float* wmat = (const float*)d_in[2];   // (128, 64)
  const float* avec = (const float*)d_in[3];   // (128, 1)
  const float* acp  = (const float*)d_in[4];   // scalar
  const float* bcp  = (const float*)d_in[5];   // scalar
  float* out = (float*)d_out;                  // (8192, 64) fp32

  // ws: f 32KB | g 32KB | hbf 1MB | pacc 4MB | pms 128KB
  float* f = (float*)d_ws;
  float* g = f + NN;
  unsigned short* hbf = (unsigned short*)(g + NN);
  float* pacc = (float*)(hbf + (size_t)NN * DOUT);
  float* pms  = pacc + (size_t)1024 * 16 * 64;

  k_h<<<NN / 4, 256, 0, stream>>>(x, wmat, avec, f, g, hbf);
  k_main<<<NN / 8, 256, 0, stream>>>(adj, f, g, hbf, acp, bcp, pacc, pms);
  k_comb<<<NN * DOUT / 256, 256, 0, stream>>>(pacc, pms, out);
}